// Round 6
// baseline (478.416 us; speedup 1.0000x reference)
//
#include <hip/hip_runtime.h>

#define NN 50000
#define NE 400000
#define DIN 32
#define DH  128
#define DOUT 16
#define NB  2
#define NBLK 49   // ceil(NN/1024)

typedef _Float16 half8 __attribute__((ext_vector_type(8)));
typedef _Float16 half4 __attribute__((ext_vector_type(4)));
typedef float    f32x4 __attribute__((ext_vector_type(4)));

#define FENCE() asm volatile("s_waitcnt lgkmcnt(0)" ::: "memory")
#define MFMA16(a, b, c) __builtin_amdgcn_mfma_f32_16x16x32_f16((a), (b), (c), 0, 0, 0)

// ---------------------------------------------------------------------------
__global__ void k_node_proj(const float* __restrict__ inp,
                            const float* __restrict__ win,
                            const float* __restrict__ bin,
                            _Float16* __restrict__ x16) {
    int gid = blockIdx.x * blockDim.x + threadIdx.x;
    if (gid >= NN * DH) return;
    int n = gid >> 7, h = gid & 127;
    float acc = bin[h];
    const float* row = inp + (size_t)n * DIN;
#pragma unroll
    for (int k = 0; k < DIN; ++k) acc = fmaf(row[k], win[k * DH + h], acc);
    x16[gid] = (_Float16)acc;
}

// ---------------------------------------------------------------------------
// Fragment-linear f16 weights (verified rounds 2-5). Per block, 24 t-tiles
// x 512 chunks of 8 f16: w1a(t0..7) w1b(4) w1c(4) w2a(4) w2b(4).
// chunk within matrix = (t*8+n)*64+l; elem j = W[t*32+(l>>4)*8+j][n*16+(l&15)]
__global__ void k_wprep(const float* __restrict__ w1a, const float* __restrict__ w1b,
                        const float* __restrict__ w1c, const float* __restrict__ w2a,
                        const float* __restrict__ w2b, _Float16* __restrict__ wf) {
    int c = blockIdx.x * blockDim.x + threadIdx.x;
    if (c >= NB * 12288) return;
    int b = c / 12288, r = c % 12288;
    int tt = r >> 9, rem = r & 511;
    const float* W; int t;
    if (tt < 8)       { W = w1a + (size_t)b * 2 * DH * DH; t = tt; }
    else if (tt < 12) { W = w1b + (size_t)b * DH * DH; t = tt - 8; }
    else if (tt < 16) { W = w1c + (size_t)b * DH * DH; t = tt - 12; }
    else if (tt < 20) { W = w2a + (size_t)b * DH * DH; t = tt - 16; }
    else              { W = w2b + (size_t)b * DH * DH; t = tt - 20; }
    int n = rem >> 6, l = rem & 63;
    int row0 = t * 32 + (l >> 4) * 8, col = n * 16 + (l & 15);
    half8 v;
#pragma unroll
    for (int j = 0; j < 8; ++j) v[j] = (_Float16)W[(size_t)(row0 + j) * DH + col];
    *(half8*)(wf + (size_t)c * 8) = v;
}

// wout [128,16] -> 256 fragment chunks (t=0..3, n=0 only)
__global__ void k_woutprep(const float* __restrict__ wout, _Float16* __restrict__ wf) {
    int c = threadIdx.x;   // 256
    int t = c >> 6, l = c & 63;
    half8 v;
#pragma unroll
    for (int j = 0; j < 8; ++j)
        v[j] = (_Float16)wout[(size_t)(t * 32 + (l >> 4) * 8 + j) * DOUT + (l & 15)];
    *(half8*)(wf + (size_t)c * 8) = v;
}

// ---------------------------------------------------------------------------
// CSR sort by dst: hist -> 3-phase scan -> scatter
__global__ void k_hist(const int* __restrict__ dstI, int* __restrict__ deg) {
    int e = blockIdx.x * blockDim.x + threadIdx.x;
    if (e < NE) atomicAdd(&deg[dstI[e]], 1);
}

__global__ void __launch_bounds__(1024) k_scanA(const int* __restrict__ deg,
                                                int* __restrict__ bsum) {
    __shared__ int ws[16];
    int tid = threadIdx.x, wv = tid >> 6, l = tid & 63;
    int i = blockIdx.x * 1024 + tid;
    int v = (i < NN) ? deg[i] : 0;
#pragma unroll
    for (int off = 32; off; off >>= 1) v += __shfl_down(v, off);
    if (l == 0) ws[wv] = v;
    __syncthreads();
    if (tid == 0) {
        int s = 0;
#pragma unroll
        for (int k = 0; k < 16; ++k) s += ws[k];
        bsum[blockIdx.x] = s;
    }
}

__global__ void k_scanB(const int* __restrict__ bsum, int* __restrict__ boff) {
    int l = threadIdx.x;  // 64 threads
    int v = (l < NBLK) ? bsum[l] : 0;
    int s = v;
#pragma unroll
    for (int off = 1; off < 64; off <<= 1) {
        int t = __shfl_up(s, off);
        if (l >= off) s += t;
    }
    if (l < NBLK) boff[l] = s - v;
}

__global__ void __launch_bounds__(1024) k_scanC(const int* __restrict__ deg,
                                                const int* __restrict__ boff,
                                                int* __restrict__ cur) {
    __shared__ int ws[16];
    int tid = threadIdx.x, wv = tid >> 6, l = tid & 63;
    int i = blockIdx.x * 1024 + tid;
    int v = (i < NN) ? deg[i] : 0;
    int s = v;
#pragma unroll
    for (int off = 1; off < 64; off <<= 1) {
        int t = __shfl_up(s, off);
        if (l >= off) s += t;
    }
    if (l == 63) ws[wv] = s;
    __syncthreads();
    if (wv == 0) {
        int t = (l < 16) ? ws[l] : 0;
#pragma unroll
        for (int off = 1; off < 16; off <<= 1) {
            int u = __shfl_up(t, off);
            if (l >= off) t += u;
        }
        if (l < 16) ws[l] = t;
    }
    __syncthreads();
    int base = boff[blockIdx.x] + (wv ? ws[wv - 1] : 0);
    if (i < NN) cur[i] = base + s - v;
}

__global__ void k_scatter(const int* __restrict__ srcI, const int* __restrict__ dstI,
                          int* __restrict__ cur, int* __restrict__ eS,
                          int* __restrict__ eD) {
    int e = blockIdx.x * blockDim.x + threadIdx.x;
    if (e >= NE) return;
    int d = dstI[e];
    int p = atomicAdd(&cur[d], 1);
    eS[p] = srcI[e];
    eD[p] = d;
}

// ---------------------------------------------------------------------------
// Edge MLP v6 = v5 + full-occupancy launch bounds + packed m3 stores.
// One 64-edge dst-sorted tile per wg; 4 waves split the 8 feature groups.
__global__ void __launch_bounds__(256, 8) k_edge5(
    const _Float16* __restrict__ xin,
    const int* __restrict__ eS, const int* __restrict__ eD,
    const half8* __restrict__ wfa, const half8* __restrict__ wfb,
    const half8* __restrict__ wfc,
    const float* __restrict__ b1a, const float* __restrict__ b1b,
    const float* __restrict__ b1c,
    float* __restrict__ agg) {
    __shared__ _Float16 sm[8192];     // 16KB: 64 edges x 128 feats (A-frag layout)
    __shared__ int slotT[4][64];

    const int tid = threadIdx.x, wv = tid >> 6, l = tid & 63;
    const int lm = l & 15, lk = l >> 4;
    const int nb = wv * 2;                    // this wave's feature groups
    const int ebase = blockIdx.x * 64;

    int srcs[4], dsts[4];
#pragma unroll
    for (int s = 0; s < 4; ++s) {
        srcs[s] = eS[ebase + s * 16 + lm];
        dsts[s] = eD[ebase + s * 16 + lm];
    }

    // run/slot machinery over 64 sorted dsts (two 32-halves), per wave
    int dl = eD[ebase + l];
    int prev = __shfl(dl, (l == 0) ? 0 : l - 1);
    bool bit = ((l & 31) == 0) ? true : (dl != prev);
    unsigned long long bal = __ballot(bit);
    unsigned mlo = (unsigned)bal, mhi = (unsigned)(bal >> 32);
    unsigned myM = (l < 32) ? mlo : mhi;
    int ll = l & 31;
    int slot_l = __popc(myM << (31 - ll)) - 1;
    if (bit) slotT[wv][(l >> 5) * 32 + slot_l] = dl;
    int nlo = __popc(mlo), nhi = __popc(mhi);

    float ba[2], bb[2], bc[2];
#pragma unroll
    for (int q = 0; q < 2; ++q) {
        ba[q] = b1a[(nb + q) * 16 + lm];
        bb[q] = b1b[(nb + q) * 16 + lm];
        bc[q] = b1c[(nb + q) * 16 + lm];
    }

    const f32x4 z = {0.f, 0.f, 0.f, 0.f};
    f32x4 acc[4][2];
    half8 aC[4], aN[4], wC[2], wN[2];

    // ---- layer 1: K=256 ([x_j | x_i])
#pragma unroll
    for (int s = 0; s < 4; ++s)
#pragma unroll
        for (int q = 0; q < 2; ++q) acc[s][q] = z;
#pragma unroll
    for (int s = 0; s < 4; ++s)
        aC[s] = *(const half8*)(xin + (size_t)srcs[s] * DH + lk * 8);
#pragma unroll
    for (int q = 0; q < 2; ++q) wC[q] = wfa[(size_t)(nb + q) * 64 + l];

    for (int t = 0; t < 8; ++t) {
        if (t < 7) {
            int t1 = t + 1;
#pragma unroll
            for (int s = 0; s < 4; ++s) {
                int node = (t1 < 4) ? srcs[s] : dsts[s];
                aN[s] = *(const half8*)(xin + (size_t)node * DH + (t1 & 3) * 32 + lk * 8);
            }
#pragma unroll
            for (int q = 0; q < 2; ++q)
                wN[q] = wfa[(size_t)(t1 * 8 + nb + q) * 64 + l];
        }
#pragma unroll
        for (int q = 0; q < 2; ++q)
#pragma unroll
            for (int s = 0; s < 4; ++s)
                acc[s][q] = MFMA16(aC[s], wC[q], acc[s][q]);
#pragma unroll
        for (int s = 0; s < 4; ++s) aC[s] = aN[s];
#pragma unroll
        for (int q = 0; q < 2; ++q) wC[q] = wN[q];
    }
    // ep1: bias+relu -> m1 (this wave's feature quarter of each subtile region)
#pragma unroll
    for (int s = 0; s < 4; ++s)
#pragma unroll
        for (int q = 0; q < 2; ++q) {
            int n = nb + q;
            int base = s * 2048 +
                       ((n >> 1) * 64 + ((n & 1) * 2 + (lm >> 3)) * 16 + lk * 4) * 8 +
                       (lm & 7);
#pragma unroll
            for (int j = 0; j < 4; ++j)
                sm[base + j * 8] = (_Float16)fmaxf(acc[s][q][j] + ba[q], 0.f);
        }
    __syncthreads();   // m1 complete (all waves)

    // ---- layer 2: K=128
#pragma unroll
    for (int s = 0; s < 4; ++s)
#pragma unroll
        for (int q = 0; q < 2; ++q) acc[s][q] = z;
#pragma unroll
    for (int q = 0; q < 2; ++q) wC[q] = wfb[(size_t)(nb + q) * 64 + l];
    for (int t = 0; t < 4; ++t) {
        if (t < 3)
#pragma unroll
            for (int q = 0; q < 2; ++q)
                wN[q] = wfb[(size_t)((t + 1) * 8 + nb + q) * 64 + l];
#pragma unroll
        for (int s = 0; s < 4; ++s)
            aC[s] = *(const half8*)&sm[s * 2048 + (t * 64 + l) * 8];
#pragma unroll
        for (int q = 0; q < 2; ++q)
#pragma unroll
            for (int s = 0; s < 4; ++s)
                acc[s][q] = MFMA16(aC[s], wC[q], acc[s][q]);
#pragma unroll
        for (int q = 0; q < 2; ++q) wC[q] = wN[q];
    }
    __syncthreads();   // all m1 reads done before in-place overwrite
#pragma unroll
    for (int s = 0; s < 4; ++s)
#pragma unroll
        for (int q = 0; q < 2; ++q) {
            int n = nb + q;
            int base = s * 2048 +
                       ((n >> 1) * 64 + ((n & 1) * 2 + (lm >> 3)) * 16 + lk * 4) * 8 +
                       (lm & 7);
#pragma unroll
            for (int j = 0; j < 4; ++j)
                sm[base + j * 8] = (_Float16)fmaxf(acc[s][q][j] + bb[q], 0.f);
        }
    __syncthreads();   // m2 complete

    // ---- layer 3: K=128
#pragma unroll
    for (int s = 0; s < 4; ++s)
#pragma unroll
        for (int q = 0; q < 2; ++q) acc[s][q] = z;
#pragma unroll
    for (int q = 0; q < 2; ++q) wC[q] = wfc[(size_t)(nb + q) * 64 + l];
    for (int t = 0; t < 4; ++t) {
        if (t < 3)
#pragma unroll
            for (int q = 0; q < 2; ++q)
                wN[q] = wfc[(size_t)((t + 1) * 8 + nb + q) * 64 + l];
#pragma unroll
        for (int s = 0; s < 4; ++s)
            aC[s] = *(const half8*)&sm[s * 2048 + (t * 64 + l) * 8];
#pragma unroll
        for (int q = 0; q < 2; ++q)
#pragma unroll
            for (int s = 0; s < 4; ++s)
                acc[s][q] = MFMA16(aC[s], wC[q], acc[s][q]);
#pragma unroll
        for (int q = 0; q < 2; ++q) wC[q] = wN[q];
    }
    __syncthreads();   // all m2 reads done before b-layout overwrite

    // ---- m3+bias -> B-layout, packed half4 stores (j=0..3 stay in one
    //      8-elem block since (s*16+lk*4)&7 in {0,4})
#pragma unroll
    for (int s = 0; s < 4; ++s) {
        int h = s >> 1;
        int e0 = (s * 16 + lk * 4) & 31;
#pragma unroll
        for (int q = 0; q < 2; ++q) {
            int n = nb + q;
            half4 v;
#pragma unroll
            for (int j = 0; j < 4; ++j) v[j] = (_Float16)(acc[s][q][j] + bc[q]);
            *(half4*)&sm[h * 4096 + (n * 64 + (e0 >> 3) * 16 + lm) * 8 + (e0 & 7)] = v;
        }
    }
    FENCE();

    // ---- MFMA segment-sum + sparse atomic scatter, per 32-edge half
#pragma unroll
    for (int h = 0; h < 2; ++h) {
        const int nsl = h ? nhi : nlo;
        half8 ind0, ind1;
#pragma unroll
        for (int e8 = 0; e8 < 8; ++e8) {
            int se = __shfl(slot_l, h * 32 + lk * 8 + e8);
            ind0[e8] = (se == lm)      ? (_Float16)1.f : (_Float16)0.f;
            ind1[e8] = (se == lm + 16) ? (_Float16)1.f : (_Float16)0.f;
        }
        int dS[4], dS2[4];
#pragma unroll
        for (int r = 0; r < 4; ++r) {
            int s = lk * 4 + r;
            dS[r]  = (s < nsl && s < 16) ? slotT[wv][h * 32 + s] : -1;
            int s2 = 16 + s;
            dS2[r] = (s2 < nsl) ? slotT[wv][h * 32 + s2] : -1;
        }
#pragma unroll
        for (int q = 0; q < 2; ++q) {
            int g = nb + q;
            half8 bfrag = *(const half8*)&sm[(h * 512 + g * 64 + l) * 8];
            f32x4 p = MFMA16(ind0, bfrag, z);
#pragma unroll
            for (int r = 0; r < 4; ++r)
                if (dS[r] >= 0)
                    unsafeAtomicAdd(agg + (size_t)dS[r] * DH + g * 16 + lm, p[r]);
            if (nsl > 16) {
                f32x4 p2 = MFMA16(ind1, bfrag, z);
#pragma unroll
                for (int r = 0; r < 4; ++r)
                    if (dS2[r] >= 0)
                        unsafeAtomicAdd(agg + (size_t)dS2[r] * DH + g * 16 + lm, p2[r]);
            }
        }
    }
}

// ---------------------------------------------------------------------------
// Node MLP via MFMA: x = relu(agg@w2a+b2a)@w2b+b2b. 16 nodes/wave,
// independent waves. LAST=true fuses the output projection (x@wout+bout)
// and skips the xo write.
template <bool LAST>
__global__ void __launch_bounds__(256, 4) k_node_mfma(
    const float* __restrict__ agg,
    const half8* __restrict__ wfa, const half8* __restrict__ wfb,
    const float* __restrict__ b2a, const float* __restrict__ b2b,
    _Float16* __restrict__ xo,
    const half8* __restrict__ woutf, const float* __restrict__ bout,
    float* __restrict__ out) {
    __shared__ _Float16 sM[4][2048];
    const int tid = threadIdx.x, wv = tid >> 6, l = tid & 63;
    const int lm = l & 15, lk = l >> 4;
    const int n0 = (blockIdx.x * 4 + wv) * 16;
    if (n0 >= NN) return;   // whole-wave OOB; no barriers in this kernel
    int nodeA = n0 + lm;
    if (nodeA >= NN) nodeA = NN - 1;

    float b2ar[8], b2br[8];
#pragma unroll
    for (int n = 0; n < 8; ++n) {
        b2ar[n] = b2a[n * 16 + lm];
        b2br[n] = b2b[n * 16 + lm];
    }

    const f32x4 z = {0.f, 0.f, 0.f, 0.f};
    f32x4 acc[8];
#pragma unroll
    for (int n = 0; n < 8; ++n) acc[n] = z;

    for (int t = 0; t < 4; ++t) {
        const float* ap = agg + (size_t)nodeA * DH + t * 32 + lk * 8;
        float4 v0 = *(const float4*)ap;
        float4 v1 = *(const float4*)(ap + 4);
        half8 a;
        a[0] = (_Float16)v0.x; a[1] = (_Float16)v0.y;
        a[2] = (_Float16)v0.z; a[3] = (_Float16)v0.w;
        a[4] = (_Float16)v1.x; a[5] = (_Float16)v1.y;
        a[6] = (_Float16)v1.z; a[7] = (_Float16)v1.w;
        const half8* wp = wfa + (size_t)t * 512 + l;
#pragma unroll
        for (int n = 0; n < 8; ++n) acc[n] = MFMA16(a, wp[n * 64], acc[n]);
    }
    _Float16* sm = sM[wv];
#pragma unroll
    for (int n = 0; n < 8; ++n) {
        int base = ((n >> 1) * 64 + ((n & 1) * 2 + (lm >> 3)) * 16 + lk * 4) * 8 +
                   (lm & 7);
#pragma unroll
        for (int j = 0; j < 4; ++j)
            sm[base + j * 8] = (_Float16)fmaxf(acc[n][j] + b2ar[n], 0.f);
    }
    FENCE();
#pragma unroll
    for (int n = 0; n < 8; ++n) acc[n] = z;
    for (int t = 0; t < 4; ++t) {
        half8 a = *(const half8*)&sm[(t * 64 + l) * 8];
        const half8* wp = wfb + (size_t)t * 512 + l;
#pragma unroll
        for (int n = 0; n < 8; ++n) acc[n] = MFMA16(a, wp[n * 64], acc[n]);
    }
    if (!LAST) {
#pragma unroll
        for (int n = 0; n < 8; ++n) {
#pragma unroll
            for (int j = 0; j < 4; ++j) {
                int nd = n0 + lk * 4 + j;
                if (nd < NN)
                    xo[(size_t)nd * DH + n * 16 + lm] = (_Float16)(acc[n][j] + b2br[n]);
            }
        }
    } else {
        // x (f16) -> frag buffer, then out = x @ wout + bout
        FENCE();   // prior frag reads complete before overwrite
#pragma unroll
        for (int n = 0; n < 8; ++n) {
            int base = ((n >> 1) * 64 + ((n & 1) * 2 + (lm >> 3)) * 16 + lk * 4) * 8 +
                       (lm & 7);
#pragma unroll
            for (int j = 0; j < 4; ++j)
                sm[base + j * 8] = (_Float16)(acc[n][j] + b2br[n]);
        }
        FENCE();
        f32x4 ao = z;
        for (int t = 0; t < 4; ++t) {
            half8 a = *(const half8*)&sm[(t * 64 + l) * 8];
            ao = MFMA16(a, woutf[t * 64 + l], ao);
        }
        float bo = bout[lm];
#pragma unroll
        for (int j = 0; j < 4; ++j) {
            int nd = n0 + lk * 4 + j;
            if (nd < NN) out[(size_t)nd * DOUT + lm] = ao[j] + bo;
        }
    }
}

// ---------------------------------------------------------------------------
extern "C" void kernel_launch(void* const* d_in, const int* in_sizes, int n_in,
                              void* d_out, int out_size, void* d_ws, size_t ws_size,
                              hipStream_t stream) {
    const float* inputs = (const float*)d_in[0];
    const int* eidx = (const int*)d_in[2];
    const int* srcI = eidx;
    const int* dstI = eidx + NE;
    const float* win  = (const float*)d_in[3];
    const float* bin_ = (const float*)d_in[4];
    const float* wout = (const float*)d_in[5];
    const float* bout = (const float*)d_in[6];
    const float* w1a = (const float*)d_in[7];
    const float* b1a = (const float*)d_in[8];
    const float* w1b = (const float*)d_in[9];
    const float* b1b = (const float*)d_in[10];
    const float* w1c = (const float*)d_in[11];
    const float* b1c = (const float*)d_in[12];
    const float* w2a = (const float*)d_in[13];
    const float* b2a = (const float*)d_in[14];
    const float* w2b = (const float*)d_in[15];
    const float* b2b = (const float*)d_in[16];

    char* p = (char*)d_ws;
    _Float16* xa = (_Float16*)p;    p += (size_t)NN * DH * 2;              // 12.8MB
    _Float16* xb = (_Float16*)p;    p += (size_t)NN * DH * 2;              // 12.8MB
    _Float16* wfAll = (_Float16*)p; p += ((size_t)NB * 12288 + 256) * 16;  // 397KB
    float* agg   = (float*)p;       p += (size_t)NN * DH * 4;              // 25.6MB
    int* deg     = (int*)p;         p += (size_t)NN * 4;
    int* cur     = (int*)p;         p += (size_t)NN * 4;
    int* bsum    = (int*)p;         p += 256;
    int* boff    = (int*)p;         p += 256;
    int* eSrt    = (int*)p;         p += (size_t)NE * 4;
    int* eDrt    = (int*)p;         p += (size_t)NE * 4;
    float* out   = (float*)d_out;
    _Float16* wfW = wfAll + (size_t)NB * 12288 * 8;   // wout frags

    k_wprep<<<(NB * 12288 + 255) / 256, 256, 0, stream>>>(w1a, w1b, w1c, w2a, w2b, wfAll);
    k_woutprep<<<1, 256, 0, stream>>>(wout, wfW);
    k_node_proj<<<(NN * DH + 255) / 256, 256, 0, stream>>>(inputs, win, bin_, xa);

    hipMemsetAsync(deg, 0, (size_t)NN * 4, stream);
    k_hist<<<(NE + 255) / 256, 256, 0, stream>>>(dstI, deg);
    k_scanA<<<NBLK, 1024, 0, stream>>>(deg, bsum);
    k_scanB<<<1, 64, 0, stream>>>(bsum, boff);
    k_scanC<<<NBLK, 1024, 0, stream>>>(deg, boff, cur);
    k_scatter<<<(NE + 255) / 256, 256, 0, stream>>>(srcI, dstI, cur, eSrt, eDrt);

    for (int b = 0; b < NB; ++b) {
        const _Float16* xi = (b & 1) ? xb : xa;
        _Float16*       xo = (b & 1) ? xa : xb;
        hipMemsetAsync(agg, 0, (size_t)NN * DH * 4, stream);
        const half8* whalf = (const half8*)(wfAll + (size_t)b * 12288 * 8);
        k_edge5<<<NE / 64, 256, 0, stream>>>(
            xi, eSrt, eDrt, whalf, whalf + 4096, whalf + 6144,
            b1a + (size_t)b * DH, b1b + (size_t)b * DH, b1c + (size_t)b * DH,
            agg);
        if (b < NB - 1)
            k_node_mfma<false><<<(NN + 63) / 64, 256, 0, stream>>>(
                agg, whalf + 8192, whalf + 10240,
                b2a + (size_t)b * DH, b2b + (size_t)b * DH,
                xo, (const half8*)wfW, bout, out);
        else
            k_node_mfma<true><<<(NN + 63) / 64, 256, 0, stream>>>(
                agg, whalf + 8192, whalf + 10240,
                b2a + (size_t)b * DH, b2b + (size_t)b * DH,
                xo, (const half8*)wfW, bout, out);
    }
}

// Round 7
// 369.991 us; speedup vs baseline: 1.2930x; 1.2930x over previous
//
#include <hip/hip_runtime.h>

#define NN 50000
#define NE 400000
#define DIN 32
#define DH  128
#define DOUT 16
#define NB  2
#define NBLK 49   // ceil(NN/1024)

typedef _Float16 half8 __attribute__((ext_vector_type(8)));
typedef _Float16 half4 __attribute__((ext_vector_type(4)));
typedef float    f32x4 __attribute__((ext_vector_type(4)));

#define FENCE() asm volatile("s_waitcnt lgkmcnt(0)" ::: "memory")
#define MFMA16(a, b, c) __builtin_amdgcn_mfma_f32_16x16x32_f16((a), (b), (c), 0, 0, 0)

// ---------------------------------------------------------------------------
__global__ void k_node_proj(const float* __restrict__ inp,
                            const float* __restrict__ win,
                            const float* __restrict__ bin,
                            _Float16* __restrict__ x16) {
    int gid = blockIdx.x * blockDim.x + threadIdx.x;
    if (gid >= NN * DH) return;
    int n = gid >> 7, h = gid & 127;
    float acc = bin[h];
    const float* row = inp + (size_t)n * DIN;
#pragma unroll
    for (int k = 0; k < DIN; ++k) acc = fmaf(row[k], win[k * DH + h], acc);
    x16[gid] = (_Float16)acc;
}

// ---------------------------------------------------------------------------
// Fragment-linear f16 weights (verified rounds 2-6). Per block, 24 t-tiles
// x 512 chunks of 8 f16: w1a(t0..7) w1b(4) w1c(4) w2a(4) w2b(4).
// chunk within matrix = (t*8+n)*64+l; elem j = W[t*32+(l>>4)*8+j][n*16+(l&15)]
__global__ void k_wprep(const float* __restrict__ w1a, const float* __restrict__ w1b,
                        const float* __restrict__ w1c, const float* __restrict__ w2a,
                        const float* __restrict__ w2b, _Float16* __restrict__ wf) {
    int c = blockIdx.x * blockDim.x + threadIdx.x;
    if (c >= NB * 12288) return;
    int b = c / 12288, r = c % 12288;
    int tt = r >> 9, rem = r & 511;
    const float* W; int t;
    if (tt < 8)       { W = w1a + (size_t)b * 2 * DH * DH; t = tt; }
    else if (tt < 12) { W = w1b + (size_t)b * DH * DH; t = tt - 8; }
    else if (tt < 16) { W = w1c + (size_t)b * DH * DH; t = tt - 12; }
    else if (tt < 20) { W = w2a + (size_t)b * DH * DH; t = tt - 16; }
    else              { W = w2b + (size_t)b * DH * DH; t = tt - 20; }
    int n = rem >> 6, l = rem & 63;
    int row0 = t * 32 + (l >> 4) * 8, col = n * 16 + (l & 15);
    half8 v;
#pragma unroll
    for (int j = 0; j < 8; ++j) v[j] = (_Float16)W[(size_t)(row0 + j) * DH + col];
    *(half8*)(wf + (size_t)c * 8) = v;
}

// wout [128,16] -> 256 fragment chunks (t=0..3, n=0 only)
__global__ void k_woutprep(const float* __restrict__ wout, _Float16* __restrict__ wf) {
    int c = threadIdx.x;   // 256
    int t = c >> 6, l = c & 63;
    half8 v;
#pragma unroll
    for (int j = 0; j < 8; ++j)
        v[j] = (_Float16)wout[(size_t)(t * 32 + (l >> 4) * 8 + j) * DOUT + (l & 15)];
    *(half8*)(wf + (size_t)c * 8) = v;
}

// ---------------------------------------------------------------------------
// CSR sort by dst: hist -> 3-phase scan -> scatter
__global__ void k_hist(const int* __restrict__ dstI, int* __restrict__ deg) {
    int e = blockIdx.x * blockDim.x + threadIdx.x;
    if (e < NE) atomicAdd(&deg[dstI[e]], 1);
}

__global__ void __launch_bounds__(1024) k_scanA(const int* __restrict__ deg,
                                                int* __restrict__ bsum) {
    __shared__ int ws[16];
    int tid = threadIdx.x, wv = tid >> 6, l = tid & 63;
    int i = blockIdx.x * 1024 + tid;
    int v = (i < NN) ? deg[i] : 0;
#pragma unroll
    for (int off = 32; off; off >>= 1) v += __shfl_down(v, off);
    if (l == 0) ws[wv] = v;
    __syncthreads();
    if (tid == 0) {
        int s = 0;
#pragma unroll
        for (int k = 0; k < 16; ++k) s += ws[k];
        bsum[blockIdx.x] = s;
    }
}

__global__ void k_scanB(const int* __restrict__ bsum, int* __restrict__ boff) {
    int l = threadIdx.x;  // 64 threads
    int v = (l < NBLK) ? bsum[l] : 0;
    int s = v;
#pragma unroll
    for (int off = 1; off < 64; off <<= 1) {
        int t = __shfl_up(s, off);
        if (l >= off) s += t;
    }
    if (l < NBLK) boff[l] = s - v;
}

__global__ void __launch_bounds__(1024) k_scanC(const int* __restrict__ deg,
                                                const int* __restrict__ boff,
                                                int* __restrict__ cur) {
    __shared__ int ws[16];
    int tid = threadIdx.x, wv = tid >> 6, l = tid & 63;
    int i = blockIdx.x * 1024 + tid;
    int v = (i < NN) ? deg[i] : 0;
    int s = v;
#pragma unroll
    for (int off = 1; off < 64; off <<= 1) {
        int t = __shfl_up(s, off);
        if (l >= off) s += t;
    }
    if (l == 63) ws[wv] = s;
    __syncthreads();
    if (wv == 0) {
        int t = (l < 16) ? ws[l] : 0;
#pragma unroll
        for (int off = 1; off < 16; off <<= 1) {
            int u = __shfl_up(t, off);
            if (l >= off) t += u;
        }
        if (l < 16) ws[l] = t;
    }
    __syncthreads();
    int base = boff[blockIdx.x] + (wv ? ws[wv - 1] : 0);
    if (i < NN) cur[i] = base + s - v;
}

__global__ void k_scatter(const int* __restrict__ srcI, const int* __restrict__ dstI,
                          int* __restrict__ cur, int* __restrict__ eS,
                          int* __restrict__ eD) {
    int e = blockIdx.x * blockDim.x + threadIdx.x;
    if (e >= NE) return;
    int d = dstI[e];
    int p = atomicAdd(&cur[d], 1);
    eS[p] = srcI[e];
    eD[p] = d;
}

// ---------------------------------------------------------------------------
// Edge MLP v7 = v5 body with launch_bounds(256,5): reg cap 102 >= ~88 live
// (56 VGPR + 32 acc) -> no spill (round-6's (256,8) cap=64 spilled, 572MB
// scratch traffic), occupancy ceiling 41 -> 62.5%.
__global__ void __launch_bounds__(256, 5) k_edge5(
    const _Float16* __restrict__ xin,
    const int* __restrict__ eS, const int* __restrict__ eD,
    const half8* __restrict__ wfa, const half8* __restrict__ wfb,
    const half8* __restrict__ wfc,
    const float* __restrict__ b1a, const float* __restrict__ b1b,
    const float* __restrict__ b1c,
    float* __restrict__ agg) {
    __shared__ _Float16 sm[8192];     // 16KB: 64 edges x 128 feats (A-frag layout)
    __shared__ int slotT[4][64];

    const int tid = threadIdx.x, wv = tid >> 6, l = tid & 63;
    const int lm = l & 15, lk = l >> 4;
    const int nb = wv * 2;                    // this wave's feature groups
    const int ebase = blockIdx.x * 64;

    int srcs[4], dsts[4];
#pragma unroll
    for (int s = 0; s < 4; ++s) {
        srcs[s] = eS[ebase + s * 16 + lm];
        dsts[s] = eD[ebase + s * 16 + lm];
    }

    // run/slot machinery over 64 sorted dsts (two 32-halves), per wave
    int dl = eD[ebase + l];
    int prev = __shfl(dl, (l == 0) ? 0 : l - 1);
    bool bit = ((l & 31) == 0) ? true : (dl != prev);
    unsigned long long bal = __ballot(bit);
    unsigned mlo = (unsigned)bal, mhi = (unsigned)(bal >> 32);
    unsigned myM = (l < 32) ? mlo : mhi;
    int ll = l & 31;
    int slot_l = __popc(myM << (31 - ll)) - 1;
    if (bit) slotT[wv][(l >> 5) * 32 + slot_l] = dl;
    int nlo = __popc(mlo), nhi = __popc(mhi);

    float ba[2], bb[2], bc[2];
#pragma unroll
    for (int q = 0; q < 2; ++q) {
        ba[q] = b1a[(nb + q) * 16 + lm];
        bb[q] = b1b[(nb + q) * 16 + lm];
        bc[q] = b1c[(nb + q) * 16 + lm];
    }

    const f32x4 z = {0.f, 0.f, 0.f, 0.f};
    f32x4 acc[4][2];
    half8 aC[4], aN[4], wC[2], wN[2];

    // ---- layer 1: K=256 ([x_j | x_i])
#pragma unroll
    for (int s = 0; s < 4; ++s)
#pragma unroll
        for (int q = 0; q < 2; ++q) acc[s][q] = z;
#pragma unroll
    for (int s = 0; s < 4; ++s)
        aC[s] = *(const half8*)(xin + (size_t)srcs[s] * DH + lk * 8);
#pragma unroll
    for (int q = 0; q < 2; ++q) wC[q] = wfa[(size_t)(nb + q) * 64 + l];

    for (int t = 0; t < 8; ++t) {
        if (t < 7) {
            int t1 = t + 1;
#pragma unroll
            for (int s = 0; s < 4; ++s) {
                int node = (t1 < 4) ? srcs[s] : dsts[s];
                aN[s] = *(const half8*)(xin + (size_t)node * DH + (t1 & 3) * 32 + lk * 8);
            }
#pragma unroll
            for (int q = 0; q < 2; ++q)
                wN[q] = wfa[(size_t)(t1 * 8 + nb + q) * 64 + l];
        }
#pragma unroll
        for (int q = 0; q < 2; ++q)
#pragma unroll
            for (int s = 0; s < 4; ++s)
                acc[s][q] = MFMA16(aC[s], wC[q], acc[s][q]);
#pragma unroll
        for (int s = 0; s < 4; ++s) aC[s] = aN[s];
#pragma unroll
        for (int q = 0; q < 2; ++q) wC[q] = wN[q];
    }
    // ep1: bias+relu -> m1 (this wave's feature quarter of each subtile region)
#pragma unroll
    for (int s = 0; s < 4; ++s)
#pragma unroll
        for (int q = 0; q < 2; ++q) {
            int n = nb + q;
            int base = s * 2048 +
                       ((n >> 1) * 64 + ((n & 1) * 2 + (lm >> 3)) * 16 + lk * 4) * 8 +
                       (lm & 7);
#pragma unroll
            for (int j = 0; j < 4; ++j)
                sm[base + j * 8] = (_Float16)fmaxf(acc[s][q][j] + ba[q], 0.f);
        }
    __syncthreads();   // m1 complete (all waves)

    // ---- layer 2: K=128
#pragma unroll
    for (int s = 0; s < 4; ++s)
#pragma unroll
        for (int q = 0; q < 2; ++q) acc[s][q] = z;
#pragma unroll
    for (int q = 0; q < 2; ++q) wC[q] = wfb[(size_t)(nb + q) * 64 + l];
    for (int t = 0; t < 4; ++t) {
        if (t < 3)
#pragma unroll
            for (int q = 0; q < 2; ++q)
                wN[q] = wfb[(size_t)((t + 1) * 8 + nb + q) * 64 + l];
#pragma unroll
        for (int s = 0; s < 4; ++s)
            aC[s] = *(const half8*)&sm[s * 2048 + (t * 64 + l) * 8];
#pragma unroll
        for (int q = 0; q < 2; ++q)
#pragma unroll
            for (int s = 0; s < 4; ++s)
                acc[s][q] = MFMA16(aC[s], wC[q], acc[s][q]);
#pragma unroll
        for (int q = 0; q < 2; ++q) wC[q] = wN[q];
    }
    __syncthreads();   // all m1 reads done before in-place overwrite
#pragma unroll
    for (int s = 0; s < 4; ++s)
#pragma unroll
        for (int q = 0; q < 2; ++q) {
            int n = nb + q;
            int base = s * 2048 +
                       ((n >> 1) * 64 + ((n & 1) * 2 + (lm >> 3)) * 16 + lk * 4) * 8 +
                       (lm & 7);
#pragma unroll
            for (int j = 0; j < 4; ++j)
                sm[base + j * 8] = (_Float16)fmaxf(acc[s][q][j] + bb[q], 0.f);
        }
    __syncthreads();   // m2 complete

    // ---- layer 3: K=128
#pragma unroll
    for (int s = 0; s < 4; ++s)
#pragma unroll
        for (int q = 0; q < 2; ++q) acc[s][q] = z;
#pragma unroll
    for (int q = 0; q < 2; ++q) wC[q] = wfc[(size_t)(nb + q) * 64 + l];
    for (int t = 0; t < 4; ++t) {
        if (t < 3)
#pragma unroll
            for (int q = 0; q < 2; ++q)
                wN[q] = wfc[(size_t)((t + 1) * 8 + nb + q) * 64 + l];
#pragma unroll
        for (int s = 0; s < 4; ++s)
            aC[s] = *(const half8*)&sm[s * 2048 + (t * 64 + l) * 8];
#pragma unroll
        for (int q = 0; q < 2; ++q)
#pragma unroll
            for (int s = 0; s < 4; ++s)
                acc[s][q] = MFMA16(aC[s], wC[q], acc[s][q]);
#pragma unroll
        for (int q = 0; q < 2; ++q) wC[q] = wN[q];
    }
    __syncthreads();   // all m2 reads done before b-layout overwrite

    // ---- m3+bias -> B-layout, packed half4 stores (j=0..3 stay in one
    //      8-elem block since (s*16+lk*4)&7 in {0,4})
#pragma unroll
    for (int s = 0; s < 4; ++s) {
        int h = s >> 1;
        int e0 = (s * 16 + lk * 4) & 31;
#pragma unroll
        for (int q = 0; q < 2; ++q) {
            int n = nb + q;
            half4 v;
#pragma unroll
            for (int j = 0; j < 4; ++j) v[j] = (_Float16)(acc[s][q][j] + bc[q]);
            *(half4*)&sm[h * 4096 + (n * 64 + (e0 >> 3) * 16 + lm) * 8 + (e0 & 7)] = v;
        }
    }
    FENCE();

    // ---- MFMA segment-sum + sparse atomic scatter, per 32-edge half
#pragma unroll
    for (int h = 0; h < 2; ++h) {
        const int nsl = h ? nhi : nlo;
        half8 ind0, ind1;
#pragma unroll
        for (int e8 = 0; e8 < 8; ++e8) {
            int se = __shfl(slot_l, h * 32 + lk * 8 + e8);
            ind0[e8] = (se == lm)      ? (_Float16)1.f : (_Float16)0.f;
            ind1[e8] = (se == lm + 16) ? (_Float16)1.f : (_Float16)0.f;
        }
        int dS[4], dS2[4];
#pragma unroll
        for (int r = 0; r < 4; ++r) {
            int s = lk * 4 + r;
            dS[r]  = (s < nsl && s < 16) ? slotT[wv][h * 32 + s] : -1;
            int s2 = 16 + s;
            dS2[r] = (s2 < nsl) ? slotT[wv][h * 32 + s2] : -1;
        }
#pragma unroll
        for (int q = 0; q < 2; ++q) {
            int g = nb + q;
            half8 bfrag = *(const half8*)&sm[(h * 512 + g * 64 + l) * 8];
            f32x4 p = MFMA16(ind0, bfrag, z);
#pragma unroll
            for (int r = 0; r < 4; ++r)
                if (dS[r] >= 0)
                    unsafeAtomicAdd(agg + (size_t)dS[r] * DH + g * 16 + lm, p[r]);
            if (nsl > 16) {
                f32x4 p2 = MFMA16(ind1, bfrag, z);
#pragma unroll
                for (int r = 0; r < 4; ++r)
                    if (dS2[r] >= 0)
                        unsafeAtomicAdd(agg + (size_t)dS2[r] * DH + g * 16 + lm, p2[r]);
            }
        }
    }
}

// ---------------------------------------------------------------------------
// Node MLP via MFMA: x = relu(agg@w2a+b2a)@w2b+b2b. 16 nodes/wave,
// independent waves. LAST=true fuses the output projection (x@wout+bout)
// and skips the xo write.
template <bool LAST>
__global__ void __launch_bounds__(256, 4) k_node_mfma(
    const float* __restrict__ agg,
    const half8* __restrict__ wfa, const half8* __restrict__ wfb,
    const float* __restrict__ b2a, const float* __restrict__ b2b,
    _Float16* __restrict__ xo,
    const half8* __restrict__ woutf, const float* __restrict__ bout,
    float* __restrict__ out) {
    __shared__ _Float16 sM[4][2048];
    const int tid = threadIdx.x, wv = tid >> 6, l = tid & 63;
    const int lm = l & 15, lk = l >> 4;
    const int n0 = (blockIdx.x * 4 + wv) * 16;
    if (n0 >= NN) return;   // whole-wave OOB; no barriers in this kernel
    int nodeA = n0 + lm;
    if (nodeA >= NN) nodeA = NN - 1;

    float b2ar[8], b2br[8];
#pragma unroll
    for (int n = 0; n < 8; ++n) {
        b2ar[n] = b2a[n * 16 + lm];
        b2br[n] = b2b[n * 16 + lm];
    }

    const f32x4 z = {0.f, 0.f, 0.f, 0.f};
    f32x4 acc[8];
#pragma unroll
    for (int n = 0; n < 8; ++n) acc[n] = z;

    for (int t = 0; t < 4; ++t) {
        const float* ap = agg + (size_t)nodeA * DH + t * 32 + lk * 8;
        float4 v0 = *(const float4*)ap;
        float4 v1 = *(const float4*)(ap + 4);
        half8 a;
        a[0] = (_Float16)v0.x; a[1] = (_Float16)v0.y;
        a[2] = (_Float16)v0.z; a[3] = (_Float16)v0.w;
        a[4] = (_Float16)v1.x; a[5] = (_Float16)v1.y;
        a[6] = (_Float16)v1.z; a[7] = (_Float16)v1.w;
        const half8* wp = wfa + (size_t)t * 512 + l;
#pragma unroll
        for (int n = 0; n < 8; ++n) acc[n] = MFMA16(a, wp[n * 64], acc[n]);
    }
    _Float16* sm = sM[wv];
#pragma unroll
    for (int n = 0; n < 8; ++n) {
        int base = ((n >> 1) * 64 + ((n & 1) * 2 + (lm >> 3)) * 16 + lk * 4) * 8 +
                   (lm & 7);
#pragma unroll
        for (int j = 0; j < 4; ++j)
            sm[base + j * 8] = (_Float16)fmaxf(acc[n][j] + b2ar[n], 0.f);
    }
    FENCE();
#pragma unroll
    for (int n = 0; n < 8; ++n) acc[n] = z;
    for (int t = 0; t < 4; ++t) {
        half8 a = *(const half8*)&sm[(t * 64 + l) * 8];
        const half8* wp = wfb + (size_t)t * 512 + l;
#pragma unroll
        for (int n = 0; n < 8; ++n) acc[n] = MFMA16(a, wp[n * 64], acc[n]);
    }
    if (!LAST) {
#pragma unroll
        for (int n = 0; n < 8; ++n) {
#pragma unroll
            for (int j = 0; j < 4; ++j) {
                int nd = n0 + lk * 4 + j;
                if (nd < NN)
                    xo[(size_t)nd * DH + n * 16 + lm] = (_Float16)(acc[n][j] + b2br[n]);
            }
        }
    } else {
        // x (f16) -> frag buffer, then out = x @ wout + bout
        FENCE();   // prior frag reads complete before overwrite
#pragma unroll
        for (int n = 0; n < 8; ++n) {
            int base = ((n >> 1) * 64 + ((n & 1) * 2 + (lm >> 3)) * 16 + lk * 4) * 8 +
                       (lm & 7);
#pragma unroll
            for (int j = 0; j < 4; ++j)
                sm[base + j * 8] = (_Float16)(acc[n][j] + b2br[n]);
        }
        FENCE();
        f32x4 ao = z;
        for (int t = 0; t < 4; ++t) {
            half8 a = *(const half8*)&sm[(t * 64 + l) * 8];
            ao = MFMA16(a, woutf[t * 64 + l], ao);
        }
        float bo = bout[lm];
#pragma unroll
        for (int j = 0; j < 4; ++j) {
            int nd = n0 + lk * 4 + j;
            if (nd < NN) out[(size_t)nd * DOUT + lm] = ao[j] + bo;
        }
    }
}

// ---------------------------------------------------------------------------
extern "C" void kernel_launch(void* const* d_in, const int* in_sizes, int n_in,
                              void* d_out, int out_size, void* d_ws, size_t ws_size,
                              hipStream_t stream) {
    const float* inputs = (const float*)d_in[0];
    const int* eidx = (const int*)d_in[2];
    const int* srcI = eidx;
    const int* dstI = eidx + NE;
    const float* win  = (const float*)d_in[3];
    const float* bin_ = (const float*)d_in[4];
    const float* wout = (const float*)d_in[5];
    const float* bout = (const float*)d_in[6];
    const float* w1a = (const float*)d_in[7];
    const float* b1a = (const float*)d_in[8];
    const float* w1b = (const float*)d_in[9];
    const float* b1b = (const float*)d_in[10];
    const float* w1c = (const float*)d_in[11];
    const float* b1c = (const float*)d_in[12];
    const float* w2a = (const float*)d_in[13];
    const float* b2a = (const float*)d_in[14];
    const float* w2b = (const float*)d_in[15];
    const float* b2b = (const float*)d_in[16];

    char* p = (char*)d_ws;
    _Float16* xa = (_Float16*)p;    p += (size_t)NN * DH * 2;              // 12.8MB
    _Float16* xb = (_Float16*)p;    p += (size_t)NN * DH * 2;              // 12.8MB
    _Float16* wfAll = (_Float16*)p; p += ((size_t)NB * 12288 + 256) * 16;  // 397KB
    float* agg   = (float*)p;       p += (size_t)NN * DH * 4;              // 25.6MB
    int* deg     = (int*)p;         p += (size_t)NN * 4;
    int* cur     = (int*)p;         p += (size_t)NN * 4;
    int* bsum    = (int*)p;         p += 256;
    int* boff    = (int*)p;         p += 256;
    int* eSrt    = (int*)p;         p += (size_t)NE * 4;
    int* eDrt    = (int*)p;         p += (size_t)NE * 4;
    float* out   = (float*)d_out;
    _Float16* wfW = wfAll + (size_t)NB * 12288 * 8;   // wout frags

    k_wprep<<<(NB * 12288 + 255) / 256, 256, 0, stream>>>(w1a, w1b, w1c, w2a, w2b, wfAll);
    k_woutprep<<<1, 256, 0, stream>>>(wout, wfW);
    k_node_proj<<<(NN * DH + 255) / 256, 256, 0, stream>>>(inputs, win, bin_, xa);

    hipMemsetAsync(deg, 0, (size_t)NN * 4, stream);
    k_hist<<<(NE + 255) / 256, 256, 0, stream>>>(dstI, deg);
    k_scanA<<<NBLK, 1024, 0, stream>>>(deg, bsum);
    k_scanB<<<1, 64, 0, stream>>>(bsum, boff);
    k_scanC<<<NBLK, 1024, 0, stream>>>(deg, boff, cur);
    k_scatter<<<(NE + 255) / 256, 256, 0, stream>>>(srcI, dstI, cur, eSrt, eDrt);

    for (int b = 0; b < NB; ++b) {
        const _Float16* xi = (b & 1) ? xb : xa;
        _Float16*       xo = (b & 1) ? xa : xb;
        hipMemsetAsync(agg, 0, (size_t)NN * DH * 4, stream);
        const half8* whalf = (const half8*)(wfAll + (size_t)b * 12288 * 8);
        k_edge5<<<NE / 64, 256, 0, stream>>>(
            xi, eSrt, eDrt, whalf, whalf + 4096, whalf + 6144,
            b1a + (size_t)b * DH, b1b + (size_t)b * DH, b1c + (size_t)b * DH,
            agg);
        if (b < NB - 1)
            k_node_mfma<false><<<(NN + 63) / 64, 256, 0, stream>>>(
                agg, whalf + 8192, whalf + 10240,
                b2a + (size_t)b * DH, b2b + (size_t)b * DH,
                xo, (const half8*)wfW, bout, out);
        else
            k_node_mfma<true><<<(NN + 63) / 64, 256, 0, stream>>>(
                agg, whalf + 8192, whalf + 10240,
                b2a + (size_t)b * DH, b2b + (size_t)b * DH,
                xo, (const half8*)wfW, bout, out);
    }
}

// Round 8
// 367.049 us; speedup vs baseline: 1.3034x; 1.0080x over previous
//
#include <hip/hip_runtime.h>

#define NN 50000
#define NE 400000
#define DIN 32
#define DH  128
#define DOUT 16
#define NB  2
#define NBLK 49   // ceil(NN/1024)

typedef _Float16 half8 __attribute__((ext_vector_type(8)));
typedef float    f32x4 __attribute__((ext_vector_type(4)));

#define FENCE() asm volatile("s_waitcnt lgkmcnt(0)" ::: "memory")
#define MFMA16(a, b, c) __builtin_amdgcn_mfma_f32_16x16x32_f16((a), (b), (c), 0, 0, 0)

// ---------------------------------------------------------------------------
__global__ void k_node_proj(const float* __restrict__ inp,
                            const float* __restrict__ win,
                            const float* __restrict__ bin,
                            _Float16* __restrict__ x16) {
    int gid = blockIdx.x * blockDim.x + threadIdx.x;
    if (gid >= NN * DH) return;
    int n = gid >> 7, h = gid & 127;
    float acc = bin[h];
    const float* row = inp + (size_t)n * DIN;
#pragma unroll
    for (int k = 0; k < DIN; ++k) acc = fmaf(row[k], win[k * DH + h], acc);
    x16[gid] = (_Float16)acc;
}

// ---------------------------------------------------------------------------
// Fragment-linear f16 weights. Per block, 24 t-tiles x 512 chunks of 8 f16:
// w1a(t0..7) w1b(4) w1c(4) w2a(4) w2b(4).
// chunk = (t*8+n)*64+l. Natural k-order (w1a/w2a/w2b):
//   elem j = W[t*32+(l>>4)*8+j][n*16+(l&15)]
// Permuted k-order for the swapped edge MLP layers 2/3 (w1b/w1c):
//   elem j = W[(2t+(j>>2))*16 + (l>>4)*4 + (j&3)][n*16+(l&15)]
// (k-slot (t,lk,j) <-> feature phi = (2t+(j>>2))*16+lk*4+(j&3), matching the
//  C-layout of the previous layer so B-frags are lane-local.)
__global__ void k_wprep(const float* __restrict__ w1a, const float* __restrict__ w1b,
                        const float* __restrict__ w1c, const float* __restrict__ w2a,
                        const float* __restrict__ w2b, _Float16* __restrict__ wf) {
    int c = blockIdx.x * blockDim.x + threadIdx.x;
    if (c >= NB * 12288) return;
    int b = c / 12288, r = c % 12288;
    int tt = r >> 9, rem = r & 511;
    const float* W; int t;
    if (tt < 8)       { W = w1a + (size_t)b * 2 * DH * DH; t = tt; }
    else if (tt < 12) { W = w1b + (size_t)b * DH * DH; t = tt - 8; }
    else if (tt < 16) { W = w1c + (size_t)b * DH * DH; t = tt - 12; }
    else if (tt < 20) { W = w2a + (size_t)b * DH * DH; t = tt - 16; }
    else              { W = w2b + (size_t)b * DH * DH; t = tt - 20; }
    bool perm = (tt >= 8 && tt < 16);
    int n = rem >> 6, l = rem & 63;
    int col = n * 16 + (l & 15);
    half8 v;
#pragma unroll
    for (int j = 0; j < 8; ++j) {
        int row = perm ? ((2 * t + (j >> 2)) * 16 + (l >> 4) * 4 + (j & 3))
                       : (t * 32 + (l >> 4) * 8 + j);
        v[j] = (_Float16)W[(size_t)row * DH + col];
    }
    *(half8*)(wf + (size_t)c * 8) = v;
}

// wout [128,16] -> 256 fragment chunks (t=0..3, n=0 only), natural k
__global__ void k_woutprep(const float* __restrict__ wout, _Float16* __restrict__ wf) {
    int c = threadIdx.x;   // 256
    int t = c >> 6, l = c & 63;
    half8 v;
#pragma unroll
    for (int j = 0; j < 8; ++j)
        v[j] = (_Float16)wout[(size_t)(t * 32 + (l >> 4) * 8 + j) * DOUT + (l & 15)];
    *(half8*)(wf + (size_t)c * 8) = v;
}

// ---------------------------------------------------------------------------
// CSR sort by dst: hist -> 3-phase scan -> scatter
__global__ void k_hist(const int* __restrict__ dstI, int* __restrict__ deg) {
    int e = blockIdx.x * blockDim.x + threadIdx.x;
    if (e < NE) atomicAdd(&deg[dstI[e]], 1);
}

__global__ void __launch_bounds__(1024) k_scanA(const int* __restrict__ deg,
                                                int* __restrict__ bsum) {
    __shared__ int ws[16];
    int tid = threadIdx.x, wv = tid >> 6, l = tid & 63;
    int i = blockIdx.x * 1024 + tid;
    int v = (i < NN) ? deg[i] : 0;
#pragma unroll
    for (int off = 32; off; off >>= 1) v += __shfl_down(v, off);
    if (l == 0) ws[wv] = v;
    __syncthreads();
    if (tid == 0) {
        int s = 0;
#pragma unroll
        for (int k = 0; k < 16; ++k) s += ws[k];
        bsum[blockIdx.x] = s;
    }
}

__global__ void k_scanB(const int* __restrict__ bsum, int* __restrict__ boff) {
    int l = threadIdx.x;  // 64 threads
    int v = (l < NBLK) ? bsum[l] : 0;
    int s = v;
#pragma unroll
    for (int off = 1; off < 64; off <<= 1) {
        int t = __shfl_up(s, off);
        if (l >= off) s += t;
    }
    if (l < NBLK) boff[l] = s - v;
}

__global__ void __launch_bounds__(1024) k_scanC(const int* __restrict__ deg,
                                                const int* __restrict__ boff,
                                                int* __restrict__ cur) {
    __shared__ int ws[16];
    int tid = threadIdx.x, wv = tid >> 6, l = tid & 63;
    int i = blockIdx.x * 1024 + tid;
    int v = (i < NN) ? deg[i] : 0;
    int s = v;
#pragma unroll
    for (int off = 1; off < 64; off <<= 1) {
        int t = __shfl_up(s, off);
        if (l >= off) s += t;
    }
    if (l == 63) ws[wv] = s;
    __syncthreads();
    if (wv == 0) {
        int t = (l < 16) ? ws[l] : 0;
#pragma unroll
        for (int off = 1; off < 16; off <<= 1) {
            int u = __shfl_up(t, off);
            if (l >= off) t += u;
        }
        if (l < 16) ws[l] = t;
    }
    __syncthreads();
    int base = boff[blockIdx.x] + (wv ? ws[wv - 1] : 0);
    if (i < NN) cur[i] = base + s - v;
}

__global__ void k_scatter(const int* __restrict__ srcI, const int* __restrict__ dstI,
                          int* __restrict__ cur, int* __restrict__ eS,
                          int* __restrict__ eD) {
    int e = blockIdx.x * blockDim.x + threadIdx.x;
    if (e >= NE) return;
    int d = dstI[e];
    int p = atomicAdd(&cur[d], 1);
    eS[p] = srcI[e];
    eD[p] = d;
}

// ---------------------------------------------------------------------------
// Edge MLP v8: swapped-operand MFMA (A=weights, B=data) so each lane keeps
// its edge (col=lm) across layers; layer boundary = packed b128 exchange
// (4 writes + 16 reads per wave, conflict-free) instead of scalar b16
// transpose stores. 64 edges/wg, 4 waves split the 8 outfeat groups.
__global__ void __launch_bounds__(256, 4) k_edge8(
    const _Float16* __restrict__ xin,
    const int* __restrict__ eS, const int* __restrict__ eD,
    const half8* __restrict__ wfa, const half8* __restrict__ wfb,
    const half8* __restrict__ wfc,
    const float* __restrict__ b1a, const float* __restrict__ b1b,
    const float* __restrict__ b1c,
    float* __restrict__ agg) {
    __shared__ _Float16 sm[8192];     // 16KB exchange / segsum buffer
    __shared__ int slotT[4][64];

    const int tid = threadIdx.x, wv = tid >> 6, l = tid & 63;
    const int lm = l & 15, lk = l >> 4;
    const int nb = wv * 2;            // this wave's outfeat groups nb, nb+1
    const int ebase = blockIdx.x * 64;

    int srcs[4], dsts[4];
#pragma unroll
    for (int s = 0; s < 4; ++s) {
        srcs[s] = eS[ebase + s * 16 + lm];
        dsts[s] = eD[ebase + s * 16 + lm];
    }

    // run/slot machinery over 64 sorted dsts (two 32-halves), per wave
    int dl = eD[ebase + l];
    int prev = __shfl(dl, (l == 0) ? 0 : l - 1);
    bool bit = ((l & 31) == 0) ? true : (dl != prev);
    unsigned long long bal = __ballot(bit);
    unsigned mlo = (unsigned)bal, mhi = (unsigned)(bal >> 32);
    unsigned myM = (l < 32) ? mlo : mhi;
    int ll = l & 31;
    int slot_l = __popc(myM << (31 - ll)) - 1;
    if (bit) slotT[wv][(l >> 5) * 32 + slot_l] = dl;
    int nlo = __popc(mlo), nhi = __popc(mhi);

    const f32x4 z = {0.f, 0.f, 0.f, 0.f};
    f32x4 acc[4][2];
    half8 aC[4], aN[4], wC[2], wN[2];

    // ---- layer 1: K=256 ([x_j | x_i]); D[row=outfeat][col=edge]
#pragma unroll
    for (int s = 0; s < 4; ++s)
#pragma unroll
        for (int q = 0; q < 2; ++q) acc[s][q] = z;
#pragma unroll
    for (int s = 0; s < 4; ++s)
        aC[s] = *(const half8*)(xin + (size_t)srcs[s] * DH + lk * 8);
#pragma unroll
    for (int q = 0; q < 2; ++q) wC[q] = wfa[(size_t)(nb + q) * 64 + l];

    for (int t = 0; t < 8; ++t) {
        if (t < 7) {
            int t1 = t + 1;
#pragma unroll
            for (int s = 0; s < 4; ++s) {
                int node = (t1 < 4) ? srcs[s] : dsts[s];
                aN[s] = *(const half8*)(xin + (size_t)node * DH + (t1 & 3) * 32 + lk * 8);
            }
#pragma unroll
            for (int q = 0; q < 2; ++q)
                wN[q] = wfa[(size_t)(t1 * 8 + nb + q) * 64 + l];
        }
#pragma unroll
        for (int q = 0; q < 2; ++q)
#pragma unroll
            for (int s = 0; s < 4; ++s)
                acc[s][q] = MFMA16(wC[q], aC[s], acc[s][q]);   // A=weights, B=data
#pragma unroll
        for (int s = 0; s < 4; ++s) aC[s] = aN[s];
#pragma unroll
        for (int q = 0; q < 2; ++q) wC[q] = wN[q];
    }
    // ep1: lane holds m1[edge lm][(nb+q)*16+lk*4+j]; pack half8 -> exchange
    {
        float4 B0 = *(const float4*)(b1a + nb * 16 + lk * 4);
        float4 B1 = *(const float4*)(b1a + (nb + 1) * 16 + lk * 4);
#pragma unroll
        for (int s = 0; s < 4; ++s) {
            half8 v;
#pragma unroll
            for (int j = 0; j < 4; ++j) {
                v[j]     = (_Float16)fmaxf(acc[s][0][j] + (&B0.x)[j], 0.f);
                v[4 + j] = (_Float16)fmaxf(acc[s][1][j] + (&B1.x)[j], 0.f);
            }
            *(half8*)&sm[((wv * 4 + s) * 64 + l) * 8] = v;
        }
    }
    __syncthreads();   // m1 exchange complete

    // ---- layer 2: K=128, B-frags (s,t) from exchange (chunk (t*4+s)*64+l)
#pragma unroll
    for (int s = 0; s < 4; ++s)
#pragma unroll
        for (int q = 0; q < 2; ++q) acc[s][q] = z;
#pragma unroll
    for (int q = 0; q < 2; ++q) wC[q] = wfb[(size_t)(nb + q) * 64 + l];
    for (int t = 0; t < 4; ++t) {
        if (t < 3)
#pragma unroll
            for (int q = 0; q < 2; ++q)
                wN[q] = wfb[(size_t)((t + 1) * 8 + nb + q) * 64 + l];
#pragma unroll
        for (int s = 0; s < 4; ++s)
            aC[s] = *(const half8*)&sm[((t * 4 + s) * 64 + l) * 8];
#pragma unroll
        for (int q = 0; q < 2; ++q)
#pragma unroll
            for (int s = 0; s < 4; ++s)
                acc[s][q] = MFMA16(wC[q], aC[s], acc[s][q]);
#pragma unroll
        for (int q = 0; q < 2; ++q) wC[q] = wN[q];
    }
    __syncthreads();   // all m1 reads done before overwrite
    {
        float4 B0 = *(const float4*)(b1b + nb * 16 + lk * 4);
        float4 B1 = *(const float4*)(b1b + (nb + 1) * 16 + lk * 4);
#pragma unroll
        for (int s = 0; s < 4; ++s) {
            half8 v;
#pragma unroll
            for (int j = 0; j < 4; ++j) {
                v[j]     = (_Float16)fmaxf(acc[s][0][j] + (&B0.x)[j], 0.f);
                v[4 + j] = (_Float16)fmaxf(acc[s][1][j] + (&B1.x)[j], 0.f);
            }
            *(half8*)&sm[((wv * 4 + s) * 64 + l) * 8] = v;
        }
    }
    __syncthreads();   // m2 exchange complete

    // ---- layer 3: K=128
#pragma unroll
    for (int s = 0; s < 4; ++s)
#pragma unroll
        for (int q = 0; q < 2; ++q) acc[s][q] = z;
#pragma unroll
    for (int q = 0; q < 2; ++q) wC[q] = wfc[(size_t)(nb + q) * 64 + l];
    for (int t = 0; t < 4; ++t) {
        if (t < 3)
#pragma unroll
            for (int q = 0; q < 2; ++q)
                wN[q] = wfc[(size_t)((t + 1) * 8 + nb + q) * 64 + l];
#pragma unroll
        for (int s = 0; s < 4; ++s)
            aC[s] = *(const half8*)&sm[((t * 4 + s) * 64 + l) * 8];
#pragma unroll
        for (int q = 0; q < 2; ++q)
#pragma unroll
            for (int s = 0; s < 4; ++s)
                acc[s][q] = MFMA16(wC[q], aC[s], acc[s][q]);
#pragma unroll
        for (int q = 0; q < 2; ++q) wC[q] = wN[q];
    }
    __syncthreads();   // all m2 reads done before segsum-layout overwrite

    // ---- m3+bias -> segsum B-layout in this wave's slice (intra-wave only):
    //  chunk (h*2+q), slot ld = lk*4+j + 16*((s&1)*2+(lm>>3)), elem lm&7,
    //  XOR-swizzled (bit4 of f16 idx) to cut bank conflicts 8->4-way.
    {
        float4 C0 = *(const float4*)(b1c + nb * 16 + lk * 4);
        float4 C1 = *(const float4*)(b1c + (nb + 1) * 16 + lk * 4);
#pragma unroll
        for (int s = 0; s < 4; ++s) {
            int h = s >> 1;
            int ldb = (s & 1) * 32 + (lm >> 3) * 16;
#pragma unroll
            for (int q = 0; q < 2; ++q) {
#pragma unroll
                for (int j = 0; j < 4; ++j) {
                    int idx = wv * 2048 +
                              ((h * 2 + q) * 64 + ldb + lk * 4 + j) * 8 + (lm & 7);
                    idx ^= (lm >> 3) << 4;
                    float bv = q ? (&C1.x)[j] : (&C0.x)[j];
                    sm[idx] = (_Float16)(acc[s][q][j] + bv);
                }
            }
        }
    }
    FENCE();

    // ---- MFMA segment-sum + sparse atomic scatter, per 32-edge half
#pragma unroll
    for (int h = 0; h < 2; ++h) {
        const int nsl = h ? nhi : nlo;
        half8 ind0, ind1;
#pragma unroll
        for (int e8 = 0; e8 < 8; ++e8) {
            int se = __shfl(slot_l, h * 32 + lk * 8 + e8);
            ind0[e8] = (se == lm)      ? (_Float16)1.f : (_Float16)0.f;
            ind1[e8] = (se == lm + 16) ? (_Float16)1.f : (_Float16)0.f;
        }
        int4 dv  = *(const int4*)&slotT[wv][h * 32 + lk * 4];
        int4 dv2 = *(const int4*)&slotT[wv][h * 32 + 16 + lk * 4];
        int dS[4], dS2[4];
#pragma unroll
        for (int r = 0; r < 4; ++r) {
            int s0 = lk * 4 + r;
            dS[r]  = (s0 < nsl && s0 < 16) ? (&dv.x)[r] : -1;
            dS2[r] = (16 + s0 < nsl) ? (&dv2.x)[r] : -1;
        }
#pragma unroll
        for (int q = 0; q < 2; ++q) {
            int g = nb + q;
            int bidx = (wv * 2048 + ((h * 2 + q) * 64 + l) * 8) ^ (((l >> 4) & 1) << 4);
            half8 bfrag = *(const half8*)&sm[bidx];
            f32x4 p = MFMA16(ind0, bfrag, z);
#pragma unroll
            for (int r = 0; r < 4; ++r)
                if (dS[r] >= 0)
                    unsafeAtomicAdd(agg + (size_t)dS[r] * DH + g * 16 + lm, p[r]);
            if (nsl > 16) {
                f32x4 p2 = MFMA16(ind1, bfrag, z);
#pragma unroll
                for (int r = 0; r < 4; ++r)
                    if (dS2[r] >= 0)
                        unsafeAtomicAdd(agg + (size_t)dS2[r] * DH + g * 16 + lm, p2[r]);
            }
        }
    }
}

// ---------------------------------------------------------------------------
// Node MLP via MFMA (unchanged, natural orientation): x = relu(agg@w2a+b2a)
// @w2b+b2b. 16 nodes/wave, independent waves. LAST fuses x@wout+bout.
template <bool LAST>
__global__ void __launch_bounds__(256, 4) k_node_mfma(
    const float* __restrict__ agg,
    const half8* __restrict__ wfa, const half8* __restrict__ wfb,
    const float* __restrict__ b2a, const float* __restrict__ b2b,
    _Float16* __restrict__ xo,
    const half8* __restrict__ woutf, const float* __restrict__ bout,
    float* __restrict__ out) {
    __shared__ _Float16 sM[4][2048];
    const int tid = threadIdx.x, wv = tid >> 6, l = tid & 63;
    const int lm = l & 15, lk = l >> 4;
    const int n0 = (blockIdx.x * 4 + wv) * 16;
    if (n0 >= NN) return;   // whole-wave OOB; no barriers in this kernel
    int nodeA = n0 + lm;
    if (nodeA >= NN) nodeA = NN - 1;

    float b2ar[8], b2br[8];
#pragma unroll
    for (int n = 0; n < 8; ++n) {
        b2ar[n] = b2a[n * 16 + lm];
        b2br[n] = b2b[n * 16 + lm];
    }

    const f32x4 z = {0.f, 0.f, 0.f, 0.f};
    f32x4 acc[8];
#pragma unroll
    for (int n = 0; n < 8; ++n) acc[n] = z;

    for (int t = 0; t < 4; ++t) {
        const float* ap = agg + (size_t)nodeA * DH + t * 32 + lk * 8;
        float4 v0 = *(const float4*)ap;
        float4 v1 = *(const float4*)(ap + 4);
        half8 a;
        a[0] = (_Float16)v0.x; a[1] = (_Float16)v0.y;
        a[2] = (_Float16)v0.z; a[3] = (_Float16)v0.w;
        a[4] = (_Float16)v1.x; a[5] = (_Float16)v1.y;
        a[6] = (_Float16)v1.z; a[7] = (_Float16)v1.w;
        const half8* wp = wfa + (size_t)t * 512 + l;
#pragma unroll
        for (int n = 0; n < 8; ++n) acc[n] = MFMA16(a, wp[n * 64], acc[n]);
    }
    _Float16* sm = sM[wv];
#pragma unroll
    for (int n = 0; n < 8; ++n) {
        int base = ((n >> 1) * 64 + ((n & 1) * 2 + (lm >> 3)) * 16 + lk * 4) * 8 +
                   (lm & 7);
#pragma unroll
        for (int j = 0; j < 4; ++j)
            sm[base + j * 8] = (_Float16)fmaxf(acc[n][j] + b2ar[n], 0.f);
    }
    FENCE();
#pragma unroll
    for (int n = 0; n < 8; ++n) acc[n] = z;
    for (int t = 0; t < 4; ++t) {
        half8 a = *(const half8*)&sm[(t * 64 + l) * 8];
        const half8* wp = wfb + (size_t)t * 512 + l;
#pragma unroll
        for (int n = 0; n < 8; ++n) acc[n] = MFMA16(a, wp[n * 64], acc[n]);
    }
    if (!LAST) {
#pragma unroll
        for (int n = 0; n < 8; ++n) {
#pragma unroll
            for (int j = 0; j < 4; ++j) {
                int nd = n0 + lk * 4 + j;
                if (nd < NN)
                    xo[(size_t)nd * DH + n * 16 + lm] = (_Float16)(acc[n][j] + b2br[n]);
            }
        }
    } else {
        FENCE();   // prior frag reads complete before overwrite
#pragma unroll
        for (int n = 0; n < 8; ++n) {
            int base = ((n >> 1) * 64 + ((n & 1) * 2 + (lm >> 3)) * 16 + lk * 4) * 8 +
                       (lm & 7);
#pragma unroll
            for (int j = 0; j < 4; ++j)
                sm[base + j * 8] = (_Float16)(acc[n][j] + b2br[n]);
        }
        FENCE();
        f32x4 ao = z;
        for (int t = 0; t < 4; ++t) {
            half8 a = *(const half8*)&sm[(t * 64 + l) * 8];
            ao = MFMA16(a, woutf[t * 64 + l], ao);
        }
        float bo = bout[lm];
#pragma unroll
        for (int j = 0; j < 4; ++j) {
            int nd = n0 + lk * 4 + j;
            if (nd < NN) out[(size_t)nd * DOUT + lm] = ao[j] + bo;
        }
    }
}

// ---------------------------------------------------------------------------
extern "C" void kernel_launch(void* const* d_in, const int* in_sizes, int n_in,
                              void* d_out, int out_size, void* d_ws, size_t ws_size,
                              hipStream_t stream) {
    const float* inputs = (const float*)d_in[0];
    const int* eidx = (const int*)d_in[2];
    const int* srcI = eidx;
    const int* dstI = eidx + NE;
    const float* win  = (const float*)d_in[3];
    const float* bin_ = (const float*)d_in[4];
    const float* wout = (const float*)d_in[5];
    const float* bout = (const float*)d_in[6];
    const float* w1a = (const float*)d_in[7];
    const float* b1a = (const float*)d_in[8];
    const float* w1b = (const float*)d_in[9];
    const float* b1b = (const float*)d_in[10];
    const float* w1c = (const float*)d_in[11];
    const float* b1c = (const float*)d_in[12];
    const float* w2a = (const float*)d_in[13];
    const float* b2a = (const float*)d_in[14];
    const float* w2b = (const float*)d_in[15];
    const float* b2b = (const float*)d_in[16];

    char* p = (char*)d_ws;
    _Float16* xa = (_Float16*)p;    p += (size_t)NN * DH * 2;              // 12.8MB
    _Float16* xb = (_Float16*)p;    p += (size_t)NN * DH * 2;              // 12.8MB
    _Float16* wfAll = (_Float16*)p; p += ((size_t)NB * 12288 + 256) * 16;  // 397KB
    float* agg   = (float*)p;       p += (size_t)NN * DH * 4;              // 25.6MB
    int* deg     = (int*)p;         p += (size_t)NN * 4;
    int* cur     = (int*)p;         p += (size_t)NN * 4;
    int* bsum    = (int*)p;         p += 256;
    int* boff    = (int*)p;         p += 256;
    int* eSrt    = (int*)p;         p += (size_t)NE * 4;
    int* eDrt    = (int*)p;         p += (size_t)NE * 4;
    float* out   = (float*)d_out;
    _Float16* wfW = wfAll + (size_t)NB * 12288 * 8;   // wout frags

    k_wprep<<<(NB * 12288 + 255) / 256, 256, 0, stream>>>(w1a, w1b, w1c, w2a, w2b, wfAll);
    k_woutprep<<<1, 256, 0, stream>>>(wout, wfW);
    k_node_proj<<<(NN * DH + 255) / 256, 256, 0, stream>>>(inputs, win, bin_, xa);

    hipMemsetAsync(deg, 0, (size_t)NN * 4, stream);
    k_hist<<<(NE + 255) / 256, 256, 0, stream>>>(dstI, deg);
    k_scanA<<<NBLK, 1024, 0, stream>>>(deg, bsum);
    k_scanB<<<1, 64, 0, stream>>>(bsum, boff);
    k_scanC<<<NBLK, 1024, 0, stream>>>(deg, boff, cur);
    k_scatter<<<(NE + 255) / 256, 256, 0, stream>>>(srcI, dstI, cur, eSrt, eDrt);

    for (int b = 0; b < NB; ++b) {
        const _Float16* xi = (b & 1) ? xb : xa;
        _Float16*       xo = (b & 1) ? xa : xb;
        hipMemsetAsync(agg, 0, (size_t)NN * DH * 4, stream);
        const half8* whalf = (const half8*)(wfAll + (size_t)b * 12288 * 8);
        k_edge8<<<NE / 64, 256, 0, stream>>>(
            xi, eSrt, eDrt, whalf, whalf + 4096, whalf + 6144,
            b1a + (size_t)b * DH, b1b + (size_t)b * DH, b1c + (size_t)b * DH,
            agg);
        if (b < NB - 1)
            k_node_mfma<false><<<(NN + 63) / 64, 256, 0, stream>>>(
                agg, whalf + 8192, whalf + 10240,
                b2a + (size_t)b * DH, b2b + (size_t)b * DH,
                xo, (const half8*)wfW, bout, out);
        else
            k_node_mfma<true><<<(NN + 63) / 64, 256, 0, stream>>>(
                agg, whalf + 8192, whalf + 10240,
                b2a + (size_t)b * DH, b2b + (size_t)b * DH,
                xo, (const half8*)wfW, bout, out);
    }
}